// Round 3
// baseline (334.606 us; speedup 1.0000x reference)
//
#include <hip/hip_runtime.h>
#include <math.h>

#define BB 32
#define SS 4096
#define DD 1024
#define NC 16                 // chunks per batch row
#define CS (SS / NC)          // 256 source rows per block
#define NWAVE 8               // 512-thread blocks
#define ROWS_PER_WAVE (CS / NWAVE)   // 32
#define NB (ROWS_PER_WAVE / 4)       // 8 batches of 4 rows

// ---------------------------------------------------------------------------
// Kernel 1: q_proj[b][d] = sum_k query[b][k] * Wa[k][d] + bias[d]
// ---------------------------------------------------------------------------
__global__ __launch_bounds__(64) void qproj_kernel(
    const float* __restrict__ query, const float* __restrict__ Wa,
    const float* __restrict__ bias, float* __restrict__ qproj)
{
    const int tid = threadIdx.x;
    const int d   = blockIdx.x * 64 + tid;
    const int b   = blockIdx.y;

    __shared__ float qlds[DD];
    {
        const float4* qsrc = (const float4*)(query + (size_t)b * DD);
        float4* qdst = (float4*)qlds;
        #pragma unroll
        for (int j = 0; j < 4; ++j) qdst[tid + 64 * j] = qsrc[tid + 64 * j];
    }
    __syncthreads();

    const float* wp = Wa + d;
    float ac0 = 0.f, ac1 = 0.f, ac2 = 0.f, ac3 = 0.f;
    for (int k = 0; k < DD; k += 8) {
        float w0 = wp[(k + 0) * DD], w1 = wp[(k + 1) * DD];
        float w2 = wp[(k + 2) * DD], w3 = wp[(k + 3) * DD];
        float w4 = wp[(k + 4) * DD], w5 = wp[(k + 5) * DD];
        float w6 = wp[(k + 6) * DD], w7 = wp[(k + 7) * DD];
        ac0 += qlds[k + 0] * w0;  ac1 += qlds[k + 1] * w1;
        ac2 += qlds[k + 2] * w2;  ac3 += qlds[k + 3] * w3;
        ac0 += qlds[k + 4] * w4;  ac1 += qlds[k + 5] * w5;
        ac2 += qlds[k + 6] * w6;  ac3 += qlds[k + 7] * w7;
    }
    qproj[(size_t)b * DD + d] = (ac0 + ac1) + (ac2 + ac3) + bias[d];
}

// ---------------------------------------------------------------------------
// Kernel 2: flash partial, 4-row batches, 2-deep software pipeline, 8 waves.
// ---------------------------------------------------------------------------
struct Row { float4 a, b, c, d; };

__device__ __forceinline__ Row load_row(const float4* vp, int lane) {
    Row r;
    r.a = vp[lane]; r.b = vp[64 + lane]; r.c = vp[128 + lane]; r.d = vp[192 + lane];
    return r;
}

__device__ __forceinline__ float dot_row(const Row& r, const Row& q) {
    return r.a.x*q.a.x + r.a.y*q.a.y + r.a.z*q.a.z + r.a.w*q.a.w
         + r.b.x*q.b.x + r.b.y*q.b.y + r.b.z*q.b.z + r.b.w*q.b.w
         + r.c.x*q.c.x + r.c.y*q.c.y + r.c.z*q.c.z + r.c.w*q.c.w
         + r.d.x*q.d.x + r.d.y*q.d.y + r.d.z*q.d.z + r.d.w*q.d.w;
}

// 4 interleaved butterfly reduces (ILP 4, 6 deep)
__device__ __forceinline__ void reduce4(float& s0, float& s1, float& s2, float& s3) {
    #pragma unroll
    for (int off = 32; off; off >>= 1) {
        s0 += __shfl_xor(s0, off, 64);
        s1 += __shfl_xor(s1, off, 64);
        s2 += __shfl_xor(s2, off, 64);
        s3 += __shfl_xor(s3, off, 64);
    }
}

// online-softmax batch update (one rescale per 4 rows)
#define PROCESS(r0, r1, r2, r3, t)                                             \
    {                                                                          \
        float s0 = dot_row(r0, q), s1 = dot_row(r1, q);                        \
        float s2 = dot_row(r2, q), s3 = dot_row(r3, q);                        \
        reduce4(s0, s1, s2, s3);                                               \
        if (lane == 0)                                                         \
            *(float4*)(scores_w + (t) * 4) = make_float4(s0, s1, s2, s3);      \
        const float mb4 = fmaxf(fmaxf(s0, s1), fmaxf(s2, s3));                 \
        const float mn  = fmaxf(m, mb4);                                       \
        const float sc  = __expf(m - mn);                                      \
        const float p0 = __expf(s0 - mn), p1 = __expf(s1 - mn);                \
        const float p2 = __expf(s2 - mn), p3 = __expf(s3 - mn);                \
        m = mn;                                                                \
        l = l * sc + ((p0 + p1) + (p2 + p3));                                  \
        acc.a.x = acc.a.x*sc + p0*r0.a.x + p1*r1.a.x + p2*r2.a.x + p3*r3.a.x;  \
        acc.a.y = acc.a.y*sc + p0*r0.a.y + p1*r1.a.y + p2*r2.a.y + p3*r3.a.y;  \
        acc.a.z = acc.a.z*sc + p0*r0.a.z + p1*r1.a.z + p2*r2.a.z + p3*r3.a.z;  \
        acc.a.w = acc.a.w*sc + p0*r0.a.w + p1*r1.a.w + p2*r2.a.w + p3*r3.a.w;  \
        acc.b.x = acc.b.x*sc + p0*r0.b.x + p1*r1.b.x + p2*r2.b.x + p3*r3.b.x;  \
        acc.b.y = acc.b.y*sc + p0*r0.b.y + p1*r1.b.y + p2*r2.b.y + p3*r3.b.y;  \
        acc.b.z = acc.b.z*sc + p0*r0.b.z + p1*r1.b.z + p2*r2.b.z + p3*r3.b.z;  \
        acc.b.w = acc.b.w*sc + p0*r0.b.w + p1*r1.b.w + p2*r2.b.w + p3*r3.b.w;  \
        acc.c.x = acc.c.x*sc + p0*r0.c.x + p1*r1.c.x + p2*r2.c.x + p3*r3.c.x;  \
        acc.c.y = acc.c.y*sc + p0*r0.c.y + p1*r1.c.y + p2*r2.c.y + p3*r3.c.y;  \
        acc.c.z = acc.c.z*sc + p0*r0.c.z + p1*r1.c.z + p2*r2.c.z + p3*r3.c.z;  \
        acc.c.w = acc.c.w*sc + p0*r0.c.w + p1*r1.c.w + p2*r2.c.w + p3*r3.c.w;  \
        acc.d.x = acc.d.x*sc + p0*r0.d.x + p1*r1.d.x + p2*r2.d.x + p3*r3.d.x;  \
        acc.d.y = acc.d.y*sc + p0*r0.d.y + p1*r1.d.y + p2*r2.d.y + p3*r3.d.y;  \
        acc.d.z = acc.d.z*sc + p0*r0.d.z + p1*r1.d.z + p2*r2.d.z + p3*r3.d.z;  \
        acc.d.w = acc.d.w*sc + p0*r0.d.w + p1*r1.d.w + p2*r2.d.w + p3*r3.d.w;  \
    }

__global__ __launch_bounds__(512) void attn_partial_kernel(
    const float* __restrict__ values, const float* __restrict__ qproj,
    float* __restrict__ scores, float* __restrict__ pm,
    float* __restrict__ pl, float* __restrict__ pctx)
{
    const int chunk = blockIdx.x;
    const int b     = blockIdx.y;
    const int tid   = threadIdx.x;
    const int lane  = tid & 63;
    const int wave  = tid >> 6;

    const float4* qp = (const float4*)(qproj + (size_t)b * DD);
    Row q;
    q.a = qp[lane]; q.b = qp[64 + lane]; q.c = qp[128 + lane]; q.d = qp[192 + lane];

    float m = -INFINITY, l = 0.f;
    Row acc;
    acc.a = make_float4(0,0,0,0); acc.b = acc.a; acc.c = acc.a; acc.d = acc.a;

    // wave owns contiguous rows [wave*32, wave*32+32) of this chunk
    const int row0 = wave * ROWS_PER_WAVE;
    const size_t vbase = ((size_t)b * SS + (size_t)chunk * CS + row0) * DD;
    const float4* vp = (const float4*)(values + vbase);
    float* scores_w = scores + (size_t)b * SS + (size_t)chunk * CS + row0;

    // 2-deep pipeline over NB=8 batches of 4 rows (manual unroll-by-2)
    Row A0 = load_row(vp + 0*256, lane), A1 = load_row(vp + 1*256, lane);
    Row A2 = load_row(vp + 2*256, lane), A3 = load_row(vp + 3*256, lane);
    Row B0, B1, B2, B3;

    #pragma unroll
    for (int t = 0; t < NB; t += 2) {
        {   // issue loads for batch t+1, then process batch t
            const float4* nvp = vp + (size_t)(t + 1) * 4 * 256;
            B0 = load_row(nvp + 0*256, lane); B1 = load_row(nvp + 1*256, lane);
            B2 = load_row(nvp + 2*256, lane); B3 = load_row(nvp + 3*256, lane);
            PROCESS(A0, A1, A2, A3, t);
        }
        {   // issue loads for batch t+2 (if any), then process batch t+1
            if (t + 2 < NB) {
                const float4* nvp = vp + (size_t)(t + 2) * 4 * 256;
                A0 = load_row(nvp + 0*256, lane); A1 = load_row(nvp + 1*256, lane);
                A2 = load_row(nvp + 2*256, lane); A3 = load_row(nvp + 3*256, lane);
            }
            PROCESS(B0, B1, B2, B3, t + 1);
        }
    }

    // ---- block combine of the 8 wave partials ----
    __shared__ float  smx[NWAVE], slx[NWAVE];
    __shared__ float4 sacc[NWAVE][256];
    sacc[wave][lane]       = acc.a;
    sacc[wave][64 + lane]  = acc.b;
    sacc[wave][128 + lane] = acc.c;
    sacc[wave][192 + lane] = acc.d;
    if (lane == 0) { smx[wave] = m; slx[wave] = l; }
    __syncthreads();

    // threads 0..255 each own one float4 of the 1024-wide context partial
    if (tid < 256) {
        float mb = smx[0];
        #pragma unroll
        for (int w = 1; w < NWAVE; ++w) mb = fmaxf(mb, smx[w]);
        float cw[NWAVE];
        float lb = 0.f;
        #pragma unroll
        for (int w = 0; w < NWAVE; ++w) {
            cw[w] = __expf(smx[w] - mb);
            lb += cw[w] * slx[w];
        }
        float4 r = make_float4(0,0,0,0);
        #pragma unroll
        for (int w = 0; w < NWAVE; ++w) {
            const float4 t = sacc[w][tid];
            r.x += cw[w] * t.x;  r.y += cw[w] * t.y;
            r.z += cw[w] * t.z;  r.w += cw[w] * t.w;
        }
        ((float4*)pctx)[((size_t)b * NC + chunk) * 256 + tid] = r;
        if (tid == 0) {
            pm[b * NC + chunk] = mb;
            pl[b * NC + chunk] = lb;
        }
    }
}

// ---------------------------------------------------------------------------
// Kernel 3: exact recombination across the NC chunk partials.
// ---------------------------------------------------------------------------
__global__ __launch_bounds__(256) void attn_finalize_kernel(
    const float* __restrict__ pm, const float* __restrict__ pl,
    const float* __restrict__ pctx, const float* __restrict__ scores,
    float* __restrict__ out)
{
    const int b   = blockIdx.x;
    const int tid = threadIdx.x;

    float M = -INFINITY;
    #pragma unroll
    for (int c = 0; c < NC; ++c) M = fmaxf(M, pm[b * NC + c]);

    float coef[NC];
    float L = 0.f;
    #pragma unroll
    for (int c = 0; c < NC; ++c) {
        coef[c] = __expf(pm[b * NC + c] - M);
        L += coef[c] * pl[b * NC + c];
    }
    const float invL = 1.0f / L;

    {
        const float4* pc = (const float4*)pctx + (size_t)b * NC * 256;
        float4 acc = make_float4(0,0,0,0);
        #pragma unroll
        for (int c = 0; c < NC; ++c) {
            const float4 t = pc[(size_t)c * 256 + tid];
            acc.x += coef[c] * t.x;  acc.y += coef[c] * t.y;
            acc.z += coef[c] * t.z;  acc.w += coef[c] * t.w;
        }
        float4 r;
        r.x = acc.x * invL; r.y = acc.y * invL; r.z = acc.z * invL; r.w = acc.w * invL;
        ((float4*)out)[(size_t)b * 256 + tid] = r;
    }

    float* wout = out + (size_t)BB * DD;
    const float* sc = scores + (size_t)b * SS;
    for (int s = tid; s < SS; s += 256) {
        wout[(size_t)b * SS + s] = __expf(sc[s] - M) * invL;
    }
}

extern "C" void kernel_launch(void* const* d_in, const int* in_sizes, int n_in,
                              void* d_out, int out_size, void* d_ws, size_t ws_size,
                              hipStream_t stream) {
    const float* query  = (const float*)d_in[0];
    const float* values = (const float*)d_in[1];
    const float* Wa     = (const float*)d_in[2];
    const float* bias   = (const float*)d_in[3];
    float* out = (float*)d_out;
    char* ws = (char*)d_ws;

    float* qproj  = (float*)(ws);                 // 131072 B
    float* scores = (float*)(ws + 131072);        // 524288 B
    float* pm     = (float*)(ws + 655360);        // 2048 B
    float* pl     = (float*)(ws + 657408);        // 2048 B
    float* pctx   = (float*)(ws + 659456);        // 2 MiB

    dim3 g1(DD / 64, BB);
    qproj_kernel<<<g1, 64, 0, stream>>>(query, Wa, bias, qproj);

    dim3 g2(NC, BB);
    attn_partial_kernel<<<g2, 512, 0, stream>>>(values, qproj, scores, pm, pl, pctx);

    attn_finalize_kernel<<<BB, 256, 0, stream>>>(pm, pl, pctx, scores, out);
}